// Round 9
// baseline (340.044 us; speedup 1.0000x reference)
//
#include <hip/hip_runtime.h>
#include <stdint.h>

// Problem constants (B,S,D_MODEL,N_HEAD) = (4,2048,1024,16), D_K=64
#define Bv 4
#define Sv 2048
#define Dv 1024
#define Hv 16
#define DKv 64
#define BSv (Bv * Sv) // 8192

typedef unsigned short u16;
typedef __attribute__((ext_vector_type(8))) short short8;   // 8 bf16 MFMA A/B frag
typedef __attribute__((ext_vector_type(8))) unsigned short u16x8;
typedef __attribute__((ext_vector_type(4))) unsigned short u16x4;
typedef __attribute__((ext_vector_type(4))) float f32x4;    // 16x16 C/D frag
typedef __attribute__((ext_vector_type(16))) float f32x16;  // 32x32 C/D frag

__device__ __forceinline__ u16 f2bf(float f) {
  union { float f; uint32_t u; } x; x.f = f;
  uint32_t r = x.u + 0x7FFFu + ((x.u >> 16) & 1u);  // round-to-nearest-even
  return (u16)(r >> 16);
}

// async global->LDS, 16B per lane. LDS dest must be wave-uniform base + lane*16.
__device__ __forceinline__ void gl_lds16(const void* g, void* l) {
  __builtin_amdgcn_global_load_lds(
      (__attribute__((address_space(1))) void*)g,
      (__attribute__((address_space(3))) void*)l, 16, 0, 0);
}

__device__ __forceinline__ f32x4 mfma16(short8 a, short8 b, f32x4 c) {
  return __builtin_amdgcn_mfma_f32_16x16x32_bf16(a, b, c, 0, 0, 0);
}
__device__ __forceinline__ f32x16 mfma32(short8 a, short8 b, f32x16 c) {
  return __builtin_amdgcn_mfma_f32_32x32x16_bf16(a, b, c, 0, 0, 0);
}

// sum of the two bf16-truncated values packed in w (exact floats)
__device__ __forceinline__ float trsum(uint32_t w) {
  return __uint_as_float(w & 0xFFFF0000u) + __uint_as_float(w << 16);
}

// ---------------------------------------------------------------------------
// fp32 -> bf16 convert for q,k,v (blockIdx.y selects tensor). 8 elems/thread.
__global__ __launch_bounds__(256) void conv_qkv(
    const float* __restrict__ q, const float* __restrict__ k,
    const float* __restrict__ v, u16* __restrict__ qb, u16* __restrict__ kb,
    u16* __restrict__ vb) {
  const float* src = (blockIdx.y == 0) ? q : (blockIdx.y == 1 ? k : v);
  u16* dst = (blockIdx.y == 0) ? qb : (blockIdx.y == 1 ? kb : vb);
  int i = (blockIdx.x * 256 + threadIdx.x) * 8;
  const float4* s4 = (const float4*)(src + i);
  float4 a = s4[0], b = s4[1];
  u16x8 o = { f2bf(a.x), f2bf(a.y), f2bf(a.z), f2bf(a.w),
              f2bf(b.x), f2bf(b.y), f2bf(b.z), f2bf(b.w) };
  *(u16x8*)(dst + i) = o;
}

// ---------------------------------------------------------------------------
// W (fp32, [k][n]) -> W^T (bf16, [n][k]). 64x64 tiles via LDS. z selects weight.
__global__ __launch_bounds__(256) void conv_wt(
    const float* __restrict__ w0, const float* __restrict__ w1,
    const float* __restrict__ w2, const float* __restrict__ w3,
    u16* __restrict__ t0, u16* __restrict__ t1, u16* __restrict__ t2,
    u16* __restrict__ t3) {
  const float* W = (blockIdx.z == 0) ? w0 : (blockIdx.z == 1 ? w1 : (blockIdx.z == 2 ? w2 : w3));
  u16* T = (blockIdx.z == 0) ? t0 : (blockIdx.z == 1 ? t1 : (blockIdx.z == 2 ? t2 : t3));
  __shared__ u16 tile[64][72];  // tile[n][k]
  int nb = blockIdx.x * 64, kb = blockIdx.y * 64;
  int t = threadIdx.x;
#pragma unroll
  for (int p = 0; p < 4; ++p) {
    int idx = p * 256 + t;
    int r = idx >> 4;            // k row within tile
    int c4 = (idx & 15) * 4;     // n col within tile
    float4 vv = *(const float4*)(W + (size_t)(kb + r) * Dv + nb + c4);
    tile[c4 + 0][r] = f2bf(vv.x);
    tile[c4 + 1][r] = f2bf(vv.y);
    tile[c4 + 2][r] = f2bf(vv.z);
    tile[c4 + 3][r] = f2bf(vv.w);
  }
  __syncthreads();
#pragma unroll
  for (int p = 0; p < 4; ++p) {
    int idx = p * 256 + t;
    int r = idx >> 4;            // n row
    int c4 = (idx & 15) * 4;     // k col
    u16x4 o = { tile[r][c4], tile[r][c4 + 1], tile[r][c4 + 2], tile[r][c4 + 3] };
    *(u16x4*)(T + (size_t)(nb + r) * Dv + kb + c4) = o;
  }
}

// ---------------------------------------------------------------------------
// GEMM v2: C[m][n] = sum_k A[m][k]*Bt[n][k], M=8192, N=1024, K=1024, bf16.
// 128x128 tile, BK=64, 4 waves of 64x64 16x16x32 MFMA — but with the attn
// kernel's double-buffered 1-barrier K-loop: prefetch tile k+1 into the
// alternate LDS buffer right after the barrier, compute tile k concurrently.
// Halves barrier count (32->16) and gives loads a full compute phase to land
// (the m97 2-barrier structure stalls at vmcnt(0) twice per iter — at this
// shallow K=16-iter shape that stall dominated: ~51 µs/GEMM, ~320 TF).
// LDS 64 KB -> 2 blocks/CU (grid is 2/CU anyway).
// blockIdx.z selects input set; modeSel=-1 -> mode=z (QKV merged), else modeSel.
// mode 0: RoPE*0.125*log2e -> Qp   mode 1: RoPE -> Kp
// mode 2: transpose -> Vt [bh][64][s]   mode 3: fp32 -> out
__global__ __launch_bounds__(256) void gemm_bt(
    const u16* __restrict__ A0, const u16* __restrict__ A1, const u16* __restrict__ A2,
    const u16* __restrict__ B0, const u16* __restrict__ B1, const u16* __restrict__ B2,
    void* __restrict__ O0, void* __restrict__ O1, void* __restrict__ O2,
    int modeSel) {
  __shared__ u16 As[2][128 * 64];
  __shared__ u16 Bs[2][128 * 64];
  int z = blockIdx.z;
  const u16* A  = (z == 0) ? A0 : (z == 1 ? A1 : A2);
  const u16* Bt = (z == 0) ? B0 : (z == 1 ? B1 : B2);
  void* Out     = (z == 0) ? O0 : (z == 1 ? O1 : O2);
  int mode = (modeSel < 0) ? z : modeSel;

  int tid = threadIdx.x;
  int lane = tid & 63, wid = tid >> 6;
  int quad = lane >> 4, cc = lane & 15;
  int wm = (wid >> 1) * 64, wn = (wid & 1) * 64;
  int m0 = blockIdx.x * 128, n0 = blockIdx.y * 128;

  f32x4 acc[4][4];
#pragma unroll
  for (int mi = 0; mi < 4; ++mi)
#pragma unroll
    for (int ni = 0; ni < 4; ++ni) {
      f32x4 zf = {0.f, 0.f, 0.f, 0.f};
      acc[mi][ni] = zf;
    }

  // prefetch K-tile 0 into buf 0
#pragma unroll
  for (int p = 0; p < 4; ++p) {
    int slot = p * 256 + tid;
    int row = slot >> 3, cl = slot & 7;
    int cg = cl ^ (row & 7);
    gl_lds16(A + (size_t)(m0 + row) * Dv + cg * 8, &As[0][slot * 8]);
    gl_lds16(Bt + (size_t)(n0 + row) * Dv + cg * 8, &Bs[0][slot * 8]);
  }

  for (int ki = 0; ki < Dv / 64; ++ki) {
    int cur = ki & 1;
    __syncthreads();  // drains prefetch(ki); all waves past compute(ki-1)

    if (ki + 1 < Dv / 64) {
      int k1 = (ki + 1) * 64;
#pragma unroll
      for (int p = 0; p < 4; ++p) {
        int slot = p * 256 + tid;
        int row = slot >> 3, cl = slot & 7;
        int cg = cl ^ (row & 7);
        gl_lds16(A + (size_t)(m0 + row) * Dv + k1 + cg * 8, &As[1 - cur][slot * 8]);
        gl_lds16(Bt + (size_t)(n0 + row) * Dv + k1 + cg * 8, &Bs[1 - cur][slot * 8]);
      }
    }

#pragma unroll
    for (int kk = 0; kk < 2; ++kk) {
      short8 af[4], bf[4];
#pragma unroll
      for (int mi = 0; mi < 4; ++mi) {
        int row = wm + mi * 16 + cc;
        int cg = kk * 4 + quad;
        af[mi] = *(const short8*)&As[cur][row * 64 + (cg ^ (row & 7)) * 8];
      }
#pragma unroll
      for (int ni = 0; ni < 4; ++ni) {
        int row = wn + ni * 16 + cc;
        int cg = kk * 4 + quad;
        bf[ni] = *(const short8*)&Bs[cur][row * 64 + (cg ^ (row & 7)) * 8];
      }
#pragma unroll
      for (int mi = 0; mi < 4; ++mi)
#pragma unroll
        for (int ni = 0; ni < 4; ++ni)
          acc[mi][ni] = mfma16(af[mi], bf[ni], acc[mi][ni]);
    }
  }

  // Epilogue. C/D layout: col n = lane&15, row m = quad*4 + reg.
  if (mode <= 1) {
    u16* O = (u16*)Out;
    float postscale = (mode == 0) ? 0.18033688011112042f : 1.0f; // 1/8*log2e
#pragma unroll
    for (int ni = 0; ni < 4; ++ni) {
      int n = n0 + wn + ni * 16 + cc;
      int h = n >> 6, d = n & 63;
      float inv = __expf(-(float)(d & 62) * (9.210340372f / 64.0f)); // theta^{-2i/64}
      float sign = (d & 1) ? 1.0f : -1.0f;
#pragma unroll
      for (int mi = 0; mi < 4; ++mi) {
        int mB = m0 + wm + mi * 16 + quad * 4;
#pragma unroll
        for (int r = 0; r < 4; ++r) {
          int m = mB + r;
          int b = m >> 11, s = m & (Sv - 1);
          float val = acc[mi][ni][r];
          float part = __shfl_xor(val, 1);  // paired even/odd feature
          float sn, cs;
          __sincosf((float)s * inv, &sn, &cs);
          float outv = (val * cs + sign * part * sn) * postscale;
          O[((size_t)(b * Hv + h) * Sv + s) * DKv + d] = f2bf(outv);
        }
      }
    }
  } else if (mode == 2) {
    u16* O = (u16*)Out;
#pragma unroll
    for (int ni = 0; ni < 4; ++ni) {
      int n = n0 + wn + ni * 16 + cc;
      int h = n >> 6, d = n & 63;
#pragma unroll
      for (int mi = 0; mi < 4; ++mi) {
        int mB = m0 + wm + mi * 16 + quad * 4;
        int b = mB >> 11, s = mB & (Sv - 1);
        u16x4 o4 = { f2bf(acc[mi][ni][0]), f2bf(acc[mi][ni][1]),
                     f2bf(acc[mi][ni][2]), f2bf(acc[mi][ni][3]) };
        *(u16x4*)&O[((size_t)(b * Hv + h) * DKv + d) * Sv + s] = o4;
      }
    }
  } else {
    float* O = (float*)Out;
#pragma unroll
    for (int ni = 0; ni < 4; ++ni) {
      int n = n0 + wn + ni * 16 + cc;
#pragma unroll
      for (int mi = 0; mi < 4; ++mi) {
        int mB = m0 + wm + mi * 16 + quad * 4;
#pragma unroll
        for (int r = 0; r < 4; ++r)
          O[(size_t)(mB + r) * Dv + n] = acc[mi][ni][r];
      }
    }
  }
}

// ---------------------------------------------------------------------------
// Flash attention v5c (R8-proven, 102 µs) — register P-transpose with
// compile-time vector indices; l from truncated packs; dbuf K/V; 33 KB LDS.
// Qp,Kp: [bh][s][64] bf16 (Q pre-scaled by 0.125*log2e). Vt: [bh][64][s] bf16.
__global__ __launch_bounds__(256, 2) void attn(
    const u16* __restrict__ Qp, const u16* __restrict__ Kp,
    const u16* __restrict__ Vt, u16* __restrict__ ctx) {
  __shared__ u16 Ks[2][64 * 64];   // [buf][key][d], chunk-swizzled
  __shared__ u16 Vs[2][64 * 64];   // [buf][d][key], chunk-swizzled
  __shared__ float Lb[4][2][32];   // per-wave l staging [wid][qs][q_local]
  int tid = threadIdx.x;
  int lane = tid & 63, wid = tid >> 6;
  int hi = lane >> 5, c32 = lane & 31;
  int sz = (c32 & 7) ^ ((c32 >> 3) & 3);
  int bh = blockIdx.y;
  int q0 = blockIdx.x * 256 + wid * 64;
  const u16* Qh = Qp + (size_t)bh * Sv * DKv;
  const u16* Kh = Kp + (size_t)bh * Sv * DKv;
  const u16* Vh = Vt + (size_t)bh * Sv * DKv;

  // Q B-frags in registers: B[n=q=c32][k = dk*16 + hi*8 + j]
  short8 qf[2][4];
#pragma unroll
  for (int qs = 0; qs < 2; ++qs)
#pragma unroll
    for (int dk = 0; dk < 4; ++dk)
      qf[qs][dk] = *(const short8*)&Qh[(size_t)(q0 + qs * 32 + c32) * DKv + dk * 16 + hi * 8];

  f32x16 o[2][2];   // O[q][d] accum, C-layout: col=d=c32, row=q=(r&3)+8*(r>>2)+4*hi
  float lacc[2] = {0.f, 0.f};
#pragma unroll
  for (int qs = 0; qs < 2; ++qs)
#pragma unroll
    for (int dt = 0; dt < 2; ++dt)
#pragma unroll
      for (int r = 0; r < 16; ++r) o[qs][dt][r] = 0.f;

  // prefetch tile 0 into buf 0
#pragma unroll
  for (int p = 0; p < 2; ++p) {
    int slot = p * 256 + tid;
    int row = slot >> 3, cl = slot & 7;
    int cg = cl ^ ((row & 7) ^ ((row >> 3) & 3));
    gl_lds16(Kh + (size_t)row * DKv + cg * 8, &Ks[0][slot * 8]);
    gl_lds16(Vh + (size_t)row * Sv + cg * 8, &Vs[0][slot * 8]);
  }

  for (int kt = 0; kt < Sv / 64; ++kt) {
    int cur = kt & 1;
    __syncthreads();  // drains prefetch(kt); all waves past compute(kt-1)

    if (kt + 1 < Sv / 64) {
      int s1 = (kt + 1) * 64;
#pragma unroll
      for (int p = 0; p < 2; ++p) {
        int slot = p * 256 + tid;
        int row = slot >> 3, cl = slot & 7;
        int cg = cl ^ ((row & 7) ^ ((row >> 3) & 3));
        gl_lds16(Kh + (size_t)(s1 + row) * DKv + cg * 8, &Ks[1 - cur][slot * 8]);
        gl_lds16(Vh + (size_t)row * Sv + s1 + cg * 8, &Vs[1 - cur][slot * 8]);
      }
    }

#pragma unroll
    for (int qs = 0; qs < 2; ++qs) {
#pragma unroll
      for (int half = 0; half < 2; ++half) {   // 32-key half = key-tile rows
        // S^T for this half: A=K rows (half*32+c32), B=Q. C col = q = c32.
        f32x16 st;
#pragma unroll
        for (int r = 0; r < 16; ++r) st[r] = 0.f;
#pragma unroll
        for (int dk = 0; dk < 4; ++dk) {
          short8 kfv = *(const short8*)&Ks[cur][(half * 32 + c32) * 64 + (((dk * 2 + hi) ^ sz)) * 8];
          st = mfma32(kfv, qf[qs][dk], st);
        }
        // Two PV k-steps (16 keys each). Groups 2pp (lo) and 2pp+1 (hi) use
        // constant vector indices; hi-dependent keep/send via cndmask on the
        // packed dwords (absmax-proven semantics).
#pragma unroll
        for (int pp = 0; pp < 2; ++pp) {
          int pk = half * 2 + pp;
          float e0 = __builtin_amdgcn_exp2f(st[8 * pp + 0]);
          float e1 = __builtin_amdgcn_exp2f(st[8 * pp + 1]);
          float e2 = __builtin_amdgcn_exp2f(st[8 * pp + 2]);
          float e3 = __builtin_amdgcn_exp2f(st[8 * pp + 3]);
          float e4 = __builtin_amdgcn_exp2f(st[8 * pp + 4]);
          float e5 = __builtin_amdgcn_exp2f(st[8 * pp + 5]);
          float e6 = __builtin_amdgcn_exp2f(st[8 * pp + 6]);
          float e7 = __builtin_amdgcn_exp2f(st[8 * pp + 7]);
          uint32_t plo0 = __builtin_amdgcn_perm(__float_as_uint(e1), __float_as_uint(e0), 0x07060302u);
          uint32_t plo1 = __builtin_amdgcn_perm(__float_as_uint(e3), __float_as_uint(e2), 0x07060302u);
          uint32_t phi0 = __builtin_amdgcn_perm(__float_as_uint(e5), __float_as_uint(e4), 0x07060302u);
          uint32_t phi1 = __builtin_amdgcn_perm(__float_as_uint(e7), __float_as_uint(e6), 0x07060302u);
          lacc[qs] += (trsum(plo0) + trsum(plo1)) + (trsum(phi0) + trsum(phi1));
          uint32_t s0 = hi ? plo0 : phi0;   // pack pair sent to partner lane
          uint32_t s1 = hi ? plo1 : phi1;
          uint32_t r0 = (uint32_t)__shfl_xor((int)s0, 32);
          uint32_t r1 = (uint32_t)__shfl_xor((int)s1, 32);
          union { uint32_t u[4]; short8 s8; } pu;
          pu.u[0] = hi ? r0 : plo0;   // frag elems 0..3: data from h'=0 lane
          pu.u[1] = hi ? r1 : plo1;
          pu.u[2] = hi ? phi0 : r0;   // frag elems 4..7: data from h'=1 lane
          pu.u[3] = hi ? phi1 : r1;
#pragma unroll
          for (int dt = 0; dt < 2; ++dt) {
            short8 vf = *(const short8*)&Vs[cur][(dt * 32 + c32) * 64 + (((pk * 2 + hi) ^ sz)) * 8];
            o[qs][dt] = mfma32(pu.s8, vf, o[qs][dt]);
          }
        }
      }
    }
  }

  // complete l (other hi-half of keys), stage per-wave, normalize, write.
#pragma unroll
  for (int qs = 0; qs < 2; ++qs) {
    lacc[qs] += __shfl_xor(lacc[qs], 32);
    Lb[wid][qs][c32] = lacc[qs];   // both hi halves write identical value
  }
  __syncthreads();
  int b = bh >> 4, h = bh & 15;
#pragma unroll
  for (int qs = 0; qs < 2; ++qs)
#pragma unroll
    for (int r = 0; r < 16; ++r) {
      int ql = (r & 3) + 8 * (r >> 2) + 4 * hi;
      int q = q0 + qs * 32 + ql;
      float linv = 1.0f / Lb[wid][qs][ql];
#pragma unroll
      for (int dt = 0; dt < 2; ++dt) {
        int d = h * DKv + dt * 32 + c32;
        ctx[((size_t)b * Sv + q) * Dv + d] = f2bf(o[qs][dt][r] * linv);
      }
    }
}

// ---------------------------------------------------------------------------
extern "C" void kernel_launch(void* const* d_in, const int* in_sizes, int n_in,
                              void* d_out, int out_size, void* d_ws, size_t ws_size,
                              hipStream_t stream) {
  (void)in_sizes; (void)n_in; (void)out_size; (void)ws_size;
  const float* q  = (const float*)d_in[0];
  const float* k  = (const float*)d_in[1];
  const float* v  = (const float*)d_in[2];
  const float* Wq = (const float*)d_in[3];
  const float* Wk = (const float*)d_in[4];
  const float* Wv = (const float*)d_in[5];
  const float* Wo = (const float*)d_in[6];

  char* ws = (char*)d_ws;
  size_t off = 0;
  const size_t big = (size_t)BSv * Dv * sizeof(u16);   // 16 MiB
  const size_t wsz = (size_t)Dv * Dv * sizeof(u16);    // 2 MiB
  u16* qb  = (u16*)(ws + off); off += big;
  u16* kb  = (u16*)(ws + off); off += big;
  u16* vb  = (u16*)(ws + off); off += big;
  u16* Wqt = (u16*)(ws + off); off += wsz;
  u16* Wkt = (u16*)(ws + off); off += wsz;
  u16* Wvt = (u16*)(ws + off); off += wsz;
  u16* Wot = (u16*)(ws + off); off += wsz;
  u16* Qp  = (u16*)(ws + off); off += big;
  u16* Kp  = (u16*)(ws + off); off += big;
  u16* Vtr = (u16*)(ws + off); off += big;
  u16* ctx = (u16*)(ws + off); off += big;

  conv_qkv<<<dim3(BSv * Dv / (256 * 8), 3), 256, 0, stream>>>(q, k, v, qb, kb, vb);
  conv_wt<<<dim3(Dv / 64, Dv / 64, 4), 256, 0, stream>>>(Wq, Wk, Wv, Wo, Wqt, Wkt, Wvt, Wot);
  // merged Q/K/V projections: grid.z selects input set, mode = z
  gemm_bt<<<dim3(BSv / 128, Dv / 128, 3), 256, 0, stream>>>(
      qb, kb, vb, Wqt, Wkt, Wvt, Qp, Kp, Vtr, -1);
  attn<<<dim3(Sv / 256, Bv * Hv), 256, 0, stream>>>(Qp, Kp, Vtr, ctx);
  gemm_bt<<<dim3(BSv / 128, Dv / 128, 1), 256, 0, stream>>>(
      ctx, ctx, ctx, Wot, Wot, Wot, d_out, d_out, d_out, 3);
}

// Round 10
// 331.424 us; speedup vs baseline: 1.0260x; 1.0260x over previous
//
#include <hip/hip_runtime.h>
#include <stdint.h>

// Problem constants (B,S,D_MODEL,N_HEAD) = (4,2048,1024,16), D_K=64
#define Bv 4
#define Sv 2048
#define Dv 1024
#define Hv 16
#define DKv 64
#define BSv (Bv * Sv) // 8192

typedef unsigned short u16;
typedef __attribute__((ext_vector_type(8))) short short8;   // 8 bf16 MFMA A/B frag
typedef __attribute__((ext_vector_type(8))) unsigned short u16x8;
typedef __attribute__((ext_vector_type(4))) unsigned short u16x4;
typedef __attribute__((ext_vector_type(4))) float f32x4;    // 16x16 C/D frag
typedef __attribute__((ext_vector_type(16))) float f32x16;  // 32x32 C/D frag

__device__ __forceinline__ u16 f2bf(float f) {
  union { float f; uint32_t u; } x; x.f = f;
  uint32_t r = x.u + 0x7FFFu + ((x.u >> 16) & 1u);  // round-to-nearest-even
  return (u16)(r >> 16);
}

// async global->LDS, 16B per lane. LDS dest must be wave-uniform base + lane*16.
__device__ __forceinline__ void gl_lds16(const void* g, void* l) {
  __builtin_amdgcn_global_load_lds(
      (__attribute__((address_space(1))) void*)g,
      (__attribute__((address_space(3))) void*)l, 16, 0, 0);
}

__device__ __forceinline__ f32x4 mfma16(short8 a, short8 b, f32x4 c) {
  return __builtin_amdgcn_mfma_f32_16x16x32_bf16(a, b, c, 0, 0, 0);
}
__device__ __forceinline__ f32x16 mfma32(short8 a, short8 b, f32x16 c) {
  return __builtin_amdgcn_mfma_f32_32x32x16_bf16(a, b, c, 0, 0, 0);
}

// ---------------------------------------------------------------------------
// fp32 -> bf16 convert for q,k,v (blockIdx.y selects tensor). 8 elems/thread.
__global__ __launch_bounds__(256) void conv_qkv(
    const float* __restrict__ q, const float* __restrict__ k,
    const float* __restrict__ v, u16* __restrict__ qb, u16* __restrict__ kb,
    u16* __restrict__ vb) {
  const float* src = (blockIdx.y == 0) ? q : (blockIdx.y == 1 ? k : v);
  u16* dst = (blockIdx.y == 0) ? qb : (blockIdx.y == 1 ? kb : vb);
  int i = (blockIdx.x * 256 + threadIdx.x) * 8;
  const float4* s4 = (const float4*)(src + i);
  float4 a = s4[0], b = s4[1];
  u16x8 o = { f2bf(a.x), f2bf(a.y), f2bf(a.z), f2bf(a.w),
              f2bf(b.x), f2bf(b.y), f2bf(b.z), f2bf(b.w) };
  *(u16x8*)(dst + i) = o;
}

// ---------------------------------------------------------------------------
// W (fp32, [k][n]) -> W^T (bf16, [n][k]). 64x64 tiles via LDS. z selects weight.
__global__ __launch_bounds__(256) void conv_wt(
    const float* __restrict__ w0, const float* __restrict__ w1,
    const float* __restrict__ w2, const float* __restrict__ w3,
    u16* __restrict__ t0, u16* __restrict__ t1, u16* __restrict__ t2,
    u16* __restrict__ t3) {
  const float* W = (blockIdx.z == 0) ? w0 : (blockIdx.z == 1 ? w1 : (blockIdx.z == 2 ? w2 : w3));
  u16* T = (blockIdx.z == 0) ? t0 : (blockIdx.z == 1 ? t1 : (blockIdx.z == 2 ? t2 : t3));
  __shared__ u16 tile[64][72];  // tile[n][k]
  int nb = blockIdx.x * 64, kb = blockIdx.y * 64;
  int t = threadIdx.x;
#pragma unroll
  for (int p = 0; p < 4; ++p) {
    int idx = p * 256 + t;
    int r = idx >> 4;            // k row within tile
    int c4 = (idx & 15) * 4;     // n col within tile
    float4 vv = *(const float4*)(W + (size_t)(kb + r) * Dv + nb + c4);
    tile[c4 + 0][r] = f2bf(vv.x);
    tile[c4 + 1][r] = f2bf(vv.y);
    tile[c4 + 2][r] = f2bf(vv.z);
    tile[c4 + 3][r] = f2bf(vv.w);
  }
  __syncthreads();
#pragma unroll
  for (int p = 0; p < 4; ++p) {
    int idx = p * 256 + t;
    int r = idx >> 4;            // n row
    int c4 = (idx & 15) * 4;     // k col
    u16x4 o = { tile[r][c4], tile[r][c4 + 1], tile[r][c4 + 2], tile[r][c4 + 3] };
    *(u16x4*)(T + (size_t)(nb + r) * Dv + kb + c4) = o;
  }
}

// ---------------------------------------------------------------------------
// GEMM: C[m][n] = sum_k A[m][k]*Bt[n][k], M=8192, N=1024, K=1024, bf16.
// 128x128 tile, BK=64, 4 waves of 64x64 16x16x32 MFMA, double-buffered
// 1-barrier K-loop (R9: neutral vs 2-barrier — kept for fewer launches).
// blockIdx.z selects input set; modeSel=-1 -> mode=z (QKV merged), else modeSel.
// mode 0: RoPE*0.125*log2e -> Qp   mode 1: RoPE -> Kp
// mode 2: transpose -> Vt [bh][64][s]   mode 3: fp32 -> out
__global__ __launch_bounds__(256) void gemm_bt(
    const u16* __restrict__ A0, const u16* __restrict__ A1, const u16* __restrict__ A2,
    const u16* __restrict__ B0, const u16* __restrict__ B1, const u16* __restrict__ B2,
    void* __restrict__ O0, void* __restrict__ O1, void* __restrict__ O2,
    int modeSel) {
  __shared__ u16 As[2][128 * 64];
  __shared__ u16 Bs[2][128 * 64];
  int z = blockIdx.z;
  const u16* A  = (z == 0) ? A0 : (z == 1 ? A1 : A2);
  const u16* Bt = (z == 0) ? B0 : (z == 1 ? B1 : B2);
  void* Out     = (z == 0) ? O0 : (z == 1 ? O1 : O2);
  int mode = (modeSel < 0) ? z : modeSel;

  int tid = threadIdx.x;
  int lane = tid & 63, wid = tid >> 6;
  int quad = lane >> 4, cc = lane & 15;
  int wm = (wid >> 1) * 64, wn = (wid & 1) * 64;
  int m0 = blockIdx.x * 128, n0 = blockIdx.y * 128;

  f32x4 acc[4][4];
#pragma unroll
  for (int mi = 0; mi < 4; ++mi)
#pragma unroll
    for (int ni = 0; ni < 4; ++ni) {
      f32x4 zf = {0.f, 0.f, 0.f, 0.f};
      acc[mi][ni] = zf;
    }

  // prefetch K-tile 0 into buf 0
#pragma unroll
  for (int p = 0; p < 4; ++p) {
    int slot = p * 256 + tid;
    int row = slot >> 3, cl = slot & 7;
    int cg = cl ^ (row & 7);
    gl_lds16(A + (size_t)(m0 + row) * Dv + cg * 8, &As[0][slot * 8]);
    gl_lds16(Bt + (size_t)(n0 + row) * Dv + cg * 8, &Bs[0][slot * 8]);
  }

  for (int ki = 0; ki < Dv / 64; ++ki) {
    int cur = ki & 1;
    __syncthreads();  // drains prefetch(ki); all waves past compute(ki-1)

    if (ki + 1 < Dv / 64) {
      int k1 = (ki + 1) * 64;
#pragma unroll
      for (int p = 0; p < 4; ++p) {
        int slot = p * 256 + tid;
        int row = slot >> 3, cl = slot & 7;
        int cg = cl ^ (row & 7);
        gl_lds16(A + (size_t)(m0 + row) * Dv + k1 + cg * 8, &As[1 - cur][slot * 8]);
        gl_lds16(Bt + (size_t)(n0 + row) * Dv + k1 + cg * 8, &Bs[1 - cur][slot * 8]);
      }
    }

#pragma unroll
    for (int kk = 0; kk < 2; ++kk) {
      short8 af[4], bf[4];
#pragma unroll
      for (int mi = 0; mi < 4; ++mi) {
        int row = wm + mi * 16 + cc;
        int cg = kk * 4 + quad;
        af[mi] = *(const short8*)&As[cur][row * 64 + (cg ^ (row & 7)) * 8];
      }
#pragma unroll
      for (int ni = 0; ni < 4; ++ni) {
        int row = wn + ni * 16 + cc;
        int cg = kk * 4 + quad;
        bf[ni] = *(const short8*)&Bs[cur][row * 64 + (cg ^ (row & 7)) * 8];
      }
#pragma unroll
      for (int mi = 0; mi < 4; ++mi)
#pragma unroll
        for (int ni = 0; ni < 4; ++ni)
          acc[mi][ni] = mfma16(af[mi], bf[ni], acc[mi][ni]);
    }
  }

  // Epilogue. C/D layout: col n = lane&15, row m = quad*4 + reg.
  if (mode <= 1) {
    u16* O = (u16*)Out;
    float postscale = (mode == 0) ? 0.18033688011112042f : 1.0f; // 1/8*log2e
#pragma unroll
    for (int ni = 0; ni < 4; ++ni) {
      int n = n0 + wn + ni * 16 + cc;
      int h = n >> 6, d = n & 63;
      float inv = __expf(-(float)(d & 62) * (9.210340372f / 64.0f)); // theta^{-2i/64}
      float sign = (d & 1) ? 1.0f : -1.0f;
#pragma unroll
      for (int mi = 0; mi < 4; ++mi) {
        int mB = m0 + wm + mi * 16 + quad * 4;
#pragma unroll
        for (int r = 0; r < 4; ++r) {
          int m = mB + r;
          int b = m >> 11, s = m & (Sv - 1);
          float val = acc[mi][ni][r];
          float part = __shfl_xor(val, 1);  // paired even/odd feature
          float sn, cs;
          __sincosf((float)s * inv, &sn, &cs);
          float outv = (val * cs + sign * part * sn) * postscale;
          O[((size_t)(b * Hv + h) * Sv + s) * DKv + d] = f2bf(outv);
        }
      }
    }
  } else if (mode == 2) {
    u16* O = (u16*)Out;
#pragma unroll
    for (int ni = 0; ni < 4; ++ni) {
      int n = n0 + wn + ni * 16 + cc;
      int h = n >> 6, d = n & 63;
#pragma unroll
      for (int mi = 0; mi < 4; ++mi) {
        int mB = m0 + wm + mi * 16 + quad * 4;
        int b = mB >> 11, s = mB & (Sv - 1);
        u16x4 o4 = { f2bf(acc[mi][ni][0]), f2bf(acc[mi][ni][1]),
                     f2bf(acc[mi][ni][2]), f2bf(acc[mi][ni][3]) };
        *(u16x4*)&O[((size_t)(b * Hv + h) * DKv + d) * Sv + s] = o4;
      }
    }
  } else {
    float* O = (float*)Out;
#pragma unroll
    for (int ni = 0; ni < 4; ++ni) {
      int n = n0 + wn + ni * 16 + cc;
#pragma unroll
      for (int mi = 0; mi < 4; ++mi) {
        int mB = m0 + wm + mi * 16 + quad * 4;
#pragma unroll
        for (int r = 0; r < 4; ++r)
          O[(size_t)(mB + r) * Dv + n] = acc[mi][ni][r];
      }
    }
  }
}

// ---------------------------------------------------------------------------
// Flash attention v6 — v5c register P-transpose + two LDS/VALU cuts:
// (1) loop reorder half->(kf once, both qs) and pp->(vf once, both qs):
//     kf/vf fragments were re-read per qs (2x redundant) — LDS b128 reads
//     per tile drop 32 -> 16 (LDS was the dominant per-CU wall).
// (2) l via ones-B MFMA on the exchanged pu frag (v4-proven): +8 MFMA/tile,
//     -128 VALU/tile (trsum chain gone), no end shuffle, no Lb staging —
//     each lane ends holding l for exactly its o-rows; l still sums the
//     exact bf16 P the PV MFMA consumes (truncation bias cancels).
// S^T via A=K,B=Q (C col=q=c32); compile-time vector indices throughout;
// hi-dependent keep/send via cndmask on packed dwords (absmax-proven).
// K/V double-buffered, 33 KB LDS, __launch_bounds__(256,2).
// Qp,Kp: [bh][s][64] bf16 (Q pre-scaled by 0.125*log2e). Vt: [bh][64][s] bf16.
__global__ __launch_bounds__(256, 2) void attn(
    const u16* __restrict__ Qp, const u16* __restrict__ Kp,
    const u16* __restrict__ Vt, u16* __restrict__ ctx) {
  __shared__ u16 Ks[2][64 * 64];   // [buf][key][d], chunk-swizzled
  __shared__ u16 Vs[2][64 * 64];   // [buf][d][key], chunk-swizzled
  int tid = threadIdx.x;
  int lane = tid & 63, wid = tid >> 6;
  int hi = lane >> 5, c32 = lane & 31;
  int sz = (c32 & 7) ^ ((c32 >> 3) & 3);
  int bh = blockIdx.y;
  int q0 = blockIdx.x * 256 + wid * 64;
  const u16* Qh = Qp + (size_t)bh * Sv * DKv;
  const u16* Kh = Kp + (size_t)bh * Sv * DKv;
  const u16* Vh = Vt + (size_t)bh * Sv * DKv;

  const short8 ones = { (short)0x3F80, (short)0x3F80, (short)0x3F80, (short)0x3F80,
                        (short)0x3F80, (short)0x3F80, (short)0x3F80, (short)0x3F80 };

  // Q B-frags in registers: B[n=q=c32][k = dk*16 + hi*8 + j]
  short8 qf[2][4];
#pragma unroll
  for (int qs = 0; qs < 2; ++qs)
#pragma unroll
    for (int dk = 0; dk < 4; ++dk)
      qf[qs][dk] = *(const short8*)&Qh[(size_t)(q0 + qs * 32 + c32) * DKv + dk * 16 + hi * 8];

  f32x16 o[2][2];   // O[q][d] accum, C-layout: col=d=c32, row=q=(r&3)+8*(r>>2)+4*hi
  f32x16 ol[2];     // l accum (ones-MFMA row sums of bf16 P) — reg r matches o reg r
#pragma unroll
  for (int qs = 0; qs < 2; ++qs) {
#pragma unroll
    for (int dt = 0; dt < 2; ++dt)
#pragma unroll
      for (int r = 0; r < 16; ++r) o[qs][dt][r] = 0.f;
#pragma unroll
    for (int r = 0; r < 16; ++r) ol[qs][r] = 0.f;
  }

  // prefetch tile 0 into buf 0
#pragma unroll
  for (int p = 0; p < 2; ++p) {
    int slot = p * 256 + tid;
    int row = slot >> 3, cl = slot & 7;
    int cg = cl ^ ((row & 7) ^ ((row >> 3) & 3));
    gl_lds16(Kh + (size_t)row * DKv + cg * 8, &Ks[0][slot * 8]);
    gl_lds16(Vh + (size_t)row * Sv + cg * 8, &Vs[0][slot * 8]);
  }

  for (int kt = 0; kt < Sv / 64; ++kt) {
    int cur = kt & 1;
    __syncthreads();  // drains prefetch(kt); all waves past compute(kt-1)

    if (kt + 1 < Sv / 64) {
      int s1 = (kt + 1) * 64;
#pragma unroll
      for (int p = 0; p < 2; ++p) {
        int slot = p * 256 + tid;
        int row = slot >> 3, cl = slot & 7;
        int cg = cl ^ ((row & 7) ^ ((row >> 3) & 3));
        gl_lds16(Kh + (size_t)(s1 + row) * DKv + cg * 8, &Ks[1 - cur][slot * 8]);
        gl_lds16(Vh + (size_t)row * Sv + s1 + cg * 8, &Vs[1 - cur][slot * 8]);
      }
    }

#pragma unroll
    for (int half = 0; half < 2; ++half) {   // 32-key half = key-tile rows
      // K A-frags once per half, shared by both q-halves.
      short8 kf[4];
#pragma unroll
      for (int dk = 0; dk < 4; ++dk)
        kf[dk] = *(const short8*)&Ks[cur][(half * 32 + c32) * 64 + (((dk * 2 + hi) ^ sz)) * 8];

      // S^T for both q-halves: A=K rows (half*32+c32), B=Q. C col = q = c32.
      f32x16 st[2];
#pragma unroll
      for (int qs = 0; qs < 2; ++qs) {
#pragma unroll
        for (int r = 0; r < 16; ++r) st[qs][r] = 0.f;
#pragma unroll
        for (int dk = 0; dk < 4; ++dk)
          st[qs] = mfma32(kf[dk], qf[qs][dk], st[qs]);
      }

      // Two PV k-steps (16 keys each); vf loaded once, shared by both qs.
#pragma unroll
      for (int pp = 0; pp < 2; ++pp) {
        int pk = half * 2 + pp;
        short8 vf[2];
#pragma unroll
        for (int dt = 0; dt < 2; ++dt)
          vf[dt] = *(const short8*)&Vs[cur][(dt * 32 + c32) * 64 + (((pk * 2 + hi) ^ sz)) * 8];
#pragma unroll
        for (int qs = 0; qs < 2; ++qs) {
          float e0 = __builtin_amdgcn_exp2f(st[qs][8 * pp + 0]);
          float e1 = __builtin_amdgcn_exp2f(st[qs][8 * pp + 1]);
          float e2 = __builtin_amdgcn_exp2f(st[qs][8 * pp + 2]);
          float e3 = __builtin_amdgcn_exp2f(st[qs][8 * pp + 3]);
          float e4 = __builtin_amdgcn_exp2f(st[qs][8 * pp + 4]);
          float e5 = __builtin_amdgcn_exp2f(st[qs][8 * pp + 5]);
          float e6 = __builtin_amdgcn_exp2f(st[qs][8 * pp + 6]);
          float e7 = __builtin_amdgcn_exp2f(st[qs][8 * pp + 7]);
          uint32_t plo0 = __builtin_amdgcn_perm(__float_as_uint(e1), __float_as_uint(e0), 0x07060302u);
          uint32_t plo1 = __builtin_amdgcn_perm(__float_as_uint(e3), __float_as_uint(e2), 0x07060302u);
          uint32_t phi0 = __builtin_amdgcn_perm(__float_as_uint(e5), __float_as_uint(e4), 0x07060302u);
          uint32_t phi1 = __builtin_amdgcn_perm(__float_as_uint(e7), __float_as_uint(e6), 0x07060302u);
          uint32_t s0 = hi ? plo0 : phi0;   // pack pair sent to partner lane
          uint32_t s1 = hi ? plo1 : phi1;
          uint32_t r0 = (uint32_t)__shfl_xor((int)s0, 32);
          uint32_t r1 = (uint32_t)__shfl_xor((int)s1, 32);
          union { uint32_t u[4]; short8 s8; } pu;
          pu.u[0] = hi ? r0 : plo0;   // frag elems 0..3: data from h'=0 lane
          pu.u[1] = hi ? r1 : plo1;
          pu.u[2] = hi ? phi0 : r0;   // frag elems 4..7: data from h'=1 lane
          pu.u[3] = hi ? phi1 : r1;
          ol[qs] = mfma32(pu.s8, ones, ol[qs]);
          o[qs][0] = mfma32(pu.s8, vf[0], o[qs][0]);
          o[qs][1] = mfma32(pu.s8, vf[1], o[qs][1]);
        }
      }
    }
  }

  // normalize + write ctx[b][s=q][h*64+d]. ol reg r is the l of o reg r's row.
  int b = bh >> 4, h = bh & 15;
#pragma unroll
  for (int qs = 0; qs < 2; ++qs)
#pragma unroll
    for (int r = 0; r < 16; ++r) {
      int q = q0 + qs * 32 + (r & 3) + 8 * (r >> 2) + 4 * hi;
      float linv = 1.0f / ol[qs][r];
#pragma unroll
      for (int dt = 0; dt < 2; ++dt) {
        int d = h * DKv + dt * 32 + c32;
        ctx[((size_t)b * Sv + q) * Dv + d] = f2bf(o[qs][dt][r] * linv);
      }
    }
}

// ---------------------------------------------------------------------------
extern "C" void kernel_launch(void* const* d_in, const int* in_sizes, int n_in,
                              void* d_out, int out_size, void* d_ws, size_t ws_size,
                              hipStream_t stream) {
  (void)in_sizes; (void)n_in; (void)out_size; (void)ws_size;
  const float* q  = (const float*)d_in[0];
  const float* k  = (const float*)d_in[1];
  const float* v  = (const float*)d_in[2];
  const float* Wq = (const float*)d_in[3];
  const float* Wk = (const float*)d_in[4];
  const float* Wv = (const float*)d_in[5];
  const float* Wo = (const float*)d_in[6];

  char* ws = (char*)d_ws;
  size_t off = 0;
  const size_t big = (size_t)BSv * Dv * sizeof(u16);   // 16 MiB
  const size_t wsz = (size_t)Dv * Dv * sizeof(u16);    // 2 MiB
  u16* qb  = (u16*)(ws + off); off += big;
  u16* kb  = (u16*)(ws + off); off += big;
  u16* vb  = (u16*)(ws + off); off += big;
  u16* Wqt = (u16*)(ws + off); off += wsz;
  u16* Wkt = (u16*)(ws + off); off += wsz;
  u16* Wvt = (u16*)(ws + off); off += wsz;
  u16* Wot = (u16*)(ws + off); off += wsz;
  u16* Qp  = (u16*)(ws + off); off += big;
  u16* Kp  = (u16*)(ws + off); off += big;
  u16* Vtr = (u16*)(ws + off); off += big;
  u16* ctx = (u16*)(ws + off); off += big;

  conv_qkv<<<dim3(BSv * Dv / (256 * 8), 3), 256, 0, stream>>>(q, k, v, qb, kb, vb);
  conv_wt<<<dim3(Dv / 64, Dv / 64, 4), 256, 0, stream>>>(Wq, Wk, Wv, Wo, Wqt, Wkt, Wvt, Wot);
  // merged Q/K/V projections: grid.z selects input set, mode = z
  gemm_bt<<<dim3(BSv / 128, Dv / 128, 3), 256, 0, stream>>>(
      qb, kb, vb, Wqt, Wkt, Wvt, Qp, Kp, Vtr, -1);
  attn<<<dim3(Sv / 256, Bv * Hv), 256, 0, stream>>>(Qp, Kp, Vtr, ctx);
  gemm_bt<<<dim3(BSv / 128, Dv / 128, 1), 256, 0, stream>>>(
      ctx, ctx, ctx, Wot, Wot, Wot, d_out, d_out, d_out, 3);
}